// Round 18
// baseline (65.249 us; speedup 1.0000x reference)
//
#include <hip/hip_runtime.h>
#include <hip/hip_bf16.h>

typedef __attribute__((ext_vector_type(8))) short bf16x8;
typedef __attribute__((ext_vector_type(4))) short s16x4;
typedef __attribute__((ext_vector_type(4))) float f32x4;

__device__ __forceinline__ short f2b(float f) {
    __hip_bfloat16 h = __float2bfloat16(f);   // RNE
    return __builtin_bit_cast(short, h);
}

#define NPH 32
#define KC  128     // floats per row per phase (512 B f32 / 256 B bf16)

// Kernel 1: x f32 -> bf16, and y2 = 2*(x @ A^T) as bf16.
__global__ void prep_kernel(const float* __restrict__ x,
                            const float* __restrict__ A,
                            ushort* __restrict__ xb,     // [64][4096] bf16
                            ushort* __restrict__ yb) {   // [64][64] bf16
    const int tid = threadIdx.x, bid = blockIdx.x;

    const int gid = bid * 256 + tid;
    if (gid < 65536) {
        float4 v = ((const float4*)x)[gid];
        ushort4 s;
        s.x = (ushort)f2b(v.x); s.y = (ushort)f2b(v.y);
        s.z = (ushort)f2b(v.z); s.w = (ushort)f2b(v.w);
        ((ushort4*)xb)[gid] = s;
    }

    const int wave = tid >> 6, lane = tid & 63;
    const int idx = bid * 4 + wave;          // 0..4095
    const int t = idx >> 6, r = idx & 63;
    const float4* xr = (const float4*)(x + (size_t)t * 4096);
    const float4* ar = (const float4*)(A + (size_t)r * 4096);
    float s = 0.f;
    #pragma unroll
    for (int i = 0; i < 16; ++i) {
        float4 a = xr[i * 64 + lane];
        float4 b = ar[i * 64 + lane];
        s += a.x * b.x + a.y * b.y + a.z * b.z + a.w * b.w;
    }
    #pragma unroll
    for (int off = 32; off; off >>= 1) s += __shfl_xor(s, off, 64);
    if (lane == 0) yb[idx] = (ushort)f2b(2.0f * s);
}

// Kernel 2: out[64][16384] = x@W^T + y2@B^T.
// 256 blocks x 512 threads (1 block/CU). R17's traffic shape + rotation
// (proven 58.6) with staging rebuilt for DEEP MLP:
//   streamers (waves 4..7) hold SIX named VGPR banks (8 x f32x4 each) of
//   W in flight: steady-state vmcnt(40) leaves 5 banks = 40 KB/wave =
//   160 KB/CU outstanding at EVERY wait (192 peak) vs R17's LDS-capped
//   64/96 -- targeting wread's proven 512 KB/CU regime. cvt f32->bf16 in
//   streamer, XOR-swizzled ds_write to 4 x 16 KB bf16 panels; consumers
//   read bf16x8 directly (zero cvt, half the ds_reads of R17).
//   lgkmcnt(0) sits between CVTW and the bank reissue (WAR-safe).
//   __launch_bounds__(512,2) grants 256-VGPR headroom so the compiler
//   cannot serialize the banks (R14's silent failure: VGPR_Count 88).
__global__ void __launch_bounds__(512, 2)
lora_gemm(const float* __restrict__ W,      // [16384][4096]
          const float* __restrict__ Bm,     // [16384][64]
          const ushort* __restrict__ xb,    // [64][4096] bf16
          const ushort* __restrict__ yb,    // [64][64] bf16
          float* __restrict__ out) {        // [64][16384]
    __shared__ char buf[4][64 * 256];       // 4 x 16 KB bf16 panels

    const int tid  = threadIdx.x;
    const int w    = tid >> 6;              // wave 0..7
    const int lane = tid & 63;
    const int j0   = blockIdx.x << 6;       // 64 W-rows / out-cols per block
    const int p0   = blockIdx.x & 31;       // phase rotation start

    if (w >= 4) {
        // ------- STREAMER (waves 4..7): rows s16 .. s16+15 ---------------
        const int s16 = (w - 4) * 16;
        f32x4 R0[8], R1[8], R2[8], R3[8], R4[8], R5[8];

        // bank <- phase (p0+I)&31; per k: 2 rows x 512 B, lane-linear.
        #define ISSUE(BK, I)                                                \
            if ((I) < NPH) {                                                \
                const int p_ = (p0 + (I)) & 31;                             \
                _Pragma("unroll")                                           \
                for (int k = 0; k < 8; ++k) {                               \
                    const int q_ = s16 + k * 2 + (lane >> 5);               \
                    BK[k] = *(const f32x4*)((const char*)(W                 \
                        + (size_t)(j0 + q_) * 4096 + (size_t)p_ * KC)       \
                        + (lane & 31) * 16);                                \
                } }

        // cvt bank -> bf16, XOR-swizzled write into 256 B/row panel.
        #define CVTW(BK, B)                                                 \
            { char* dst_ = &buf[B][0];                                      \
              _Pragma("unroll")                                             \
              for (int k = 0; k < 8; ++k) {                                 \
                  const int q_ = s16 + k * 2 + (lane >> 5);                 \
                  s16x4 v_;                                                 \
                  v_[0] = f2b(BK[k][0]); v_[1] = f2b(BK[k][1]);             \
                  v_[2] = f2b(BK[k][2]); v_[3] = f2b(BK[k][3]);             \
                  *(s16x4*)(dst_ + q_ * 256                                 \
                      + (((lane & 31) * 8) ^ ((q_ & 7) << 4))) = v_;        \
              } }

        #define VM(N) asm volatile("s_waitcnt vmcnt(" #N ")" ::: "memory");
        #define LG()  asm volatile("s_waitcnt lgkmcnt(0)" ::: "memory");
        #define BAR() __builtin_amdgcn_s_barrier();

        // prologue: fill banks 0..5, pre-cvt phases 0..2, reissue 6..8.
        ISSUE(R0, 0) ISSUE(R1, 1) ISSUE(R2, 2)
        ISSUE(R3, 3) ISSUE(R4, 4) ISSUE(R5, 5)
        VM(40) CVTW(R0, 0) LG() ISSUE(R0, 6)
        VM(40) CVTW(R1, 1) LG() ISSUE(R1, 7)
        VM(40) CVTW(R2, 2) LG() ISSUE(R2, 8)
        BAR()                                // B_0

        // steady i=0..22: cvt phase i+3 (bank (i+3)%6 -> buf (i+3)%4),
        // reissue that bank with phase i+9. vmcnt(40) = 5 banks in flight.
        #define STEP(BK, B, I9) VM(40) CVTW(BK, B) LG() ISSUE(BK, I9) BAR()
        STEP(R3, 3,  9) STEP(R4, 0, 10) STEP(R5, 1, 11) STEP(R0, 2, 12)
        STEP(R1, 3, 13) STEP(R2, 0, 14) STEP(R3, 1, 15) STEP(R4, 2, 16)
        STEP(R5, 3, 17) STEP(R0, 0, 18) STEP(R1, 1, 19) STEP(R2, 2, 20)
        STEP(R3, 3, 21) STEP(R4, 0, 22) STEP(R5, 1, 23) STEP(R0, 2, 24)
        STEP(R1, 3, 25) STEP(R2, 0, 26) STEP(R3, 1, 27) STEP(R4, 2, 28)
        STEP(R5, 3, 29) STEP(R0, 0, 30) STEP(R1, 1, 31)

        // tail: drain cvt for phases 26..31 with exact counted vmcnt.
        VM(40) CVTW(R2, 2) LG() BAR()        // i=23, phase 26
        VM(32) CVTW(R3, 3) LG() BAR()        // i=24, phase 27
        VM(24) CVTW(R4, 0) LG() BAR()        // i=25, phase 28
        VM(16) CVTW(R5, 1) LG() BAR()        // i=26, phase 29
        VM(8)  CVTW(R0, 2) LG() BAR()        // i=27, phase 30
        VM(0)  CVTW(R1, 3) LG() BAR()        // i=28, phase 31
        BAR()                                // i=29
        BAR()                                // i=30  (32 barriers total)
        #undef STEP
        #undef ISSUE
        #undef CVTW
        #undef VM
        #undef LG
        #undef BAR
        return;
    }

    // ------- CONSUMER (waves 0..3): tokens w*16..w*16+15 -----------------
    const int c  = lane & 15;               // token row / D-col index
    const int kg = lane >> 4;               // k-group, offset kg*8
    const ushort* xrow = xb + (size_t)(w * 16 + c) * 4096 + kg * 8;

    f32x4 acc[4];
    #pragma unroll
    for (int n = 0; n < 4; ++n) acc[n] = f32x4{0.f, 0.f, 0.f, 0.f};

    for (int i = 0; i < NPH; ++i) {
        const int p = (p0 + i) & 31;
        __builtin_amdgcn_s_barrier();       // B_i: buf[i&3] ready
        const char* lb = &buf[i & 3][0];
        #pragma unroll
        for (int sl = 0; sl < 4; ++sl) {
            bf16x8 aa = *(const bf16x8*)(xrow + p * KC + sl * 32);
            #pragma unroll
            for (int n = 0; n < 4; ++n) {
                const int q = n * 16 + c;   // W-row within block = D col
                bf16x8 bb = *(const bf16x8*)(lb + q * 256
                    + ((sl * 64 + kg * 16) ^ ((q & 7) << 4)));
                acc[n] = __builtin_amdgcn_mfma_f32_16x16x32_bf16(
                    aa, bb, acc[n], 0, 0, 0);
            }
        }
    }

    // lora tail: 2 K-steps over r=64 per col-subtile
    {
        const ushort* y0 = yb + (size_t)(w * 16 + c) * 64 + kg * 8;
        #pragma unroll
        for (int n = 0; n < 4; ++n) {
            const float* br = Bm + (size_t)(j0 + n * 16 + c) * 64 + kg * 8;
            #pragma unroll
            for (int k = 0; k < 64; k += 32) {
                f32x4 w0 = *(const f32x4*)(br + k);
                f32x4 w1 = *(const f32x4*)(br + k + 4);
                bf16x8 bb;
                bb[0] = f2b(w0[0]); bb[1] = f2b(w0[1]);
                bb[2] = f2b(w0[2]); bb[3] = f2b(w0[3]);
                bb[4] = f2b(w1[0]); bb[5] = f2b(w1[1]);
                bb[6] = f2b(w1[2]); bb[7] = f2b(w1[3]);
                bf16x8 aa = *(const bf16x8*)(y0 + k);
                acc[n] = __builtin_amdgcn_mfma_f32_16x16x32_bf16(
                    aa, bb, acc[n], 0, 0, 0);
            }
        }
    }

    // store: token row = w*16 + kg*4 + r, col = j0 + n*16 + c
    #pragma unroll
    for (int n = 0; n < 4; ++n) {
        float* op = out + j0 + n * 16 + c;
        #pragma unroll
        for (int r = 0; r < 4; ++r)
            op[(size_t)(w * 16 + kg * 4 + r) * 16384] = acc[n][r];
    }
}

extern "C" void kernel_launch(void* const* d_in, const int* in_sizes, int n_in,
                              void* d_out, int out_size, void* d_ws, size_t ws_size,
                              hipStream_t stream) {
    const float* x  = (const float*)d_in[0];
    const float* W  = (const float*)d_in[1];
    const float* A  = (const float*)d_in[2];
    const float* Bm = (const float*)d_in[3];
    float* out = (float*)d_out;

    ushort* xb = (ushort*)d_ws;                          // 64*4096*2 = 524288 B
    ushort* yb = (ushort*)((char*)d_ws + 524288);        // 64*64*2   = 8192 B

    prep_kernel<<<1024, 256, 0, stream>>>(x, A, xb, yb);
    lora_gemm<<<256, 512, 0, stream>>>(W, Bm, xb, yb, out);
}